// Round 8
// baseline (302.172 us; speedup 1.0000x reference)
//
#include <hip/hip_runtime.h>
#include <math.h>

#define NB 256
#define NP 512
#define TS 128
#define GI 33
#define TAB2D (GI * GI)     // 1089
#define GV 193              // V-table nodes, h = 1/192
#define V_Lc 3.4f
#define V_0c 4.2f
#define GAMMAc 0.9f
#define ALPHAc 0.15f
#define BETAc 15.0f
#define E_INV 2e-5f
#define F_STDc 0.05f
#define G_STDc 0.02f

// light barrier: LDS-ordering only, leaves global loads/stores in flight
#define LBAR() asm volatile("s_waitcnt lgkmcnt(0)\n\ts_barrier" ::: "memory")

__device__ __forceinline__ float sigmoid_jax(float x) {
    float e = expf(-fabsf(x));
    float num = (x >= 0.f) ? 1.f : e;
    return num / (1.f + e);
}

__device__ __forceinline__ float vocf(float s) {
    float sm1 = s - 1.f;
    return V_Lc + (V_0c - V_Lc) * expf(GAMMAc * sm1)
         + (ALPHAc * V_Lc) * sm1
         + (1.f - ALPHAc) * V_Lc * (expf(-BETAc) - expf(-BETAc * sqrtf(s)));
}

// ---------------- DPP cross-lane helpers --------------------------------
template <int R>
__device__ __forceinline__ int dpp_ror(int v) {
    return __builtin_amdgcn_update_dpp(0, v, 0x120 | R, 0xf, 0xf, false);
}
template <int S>
__device__ __forceinline__ int dpp_shr(int v) {
    return __builtin_amdgcn_update_dpp(0, v, 0x110 | S, 0xf, 0xf, true);
}

__device__ __forceinline__ float wave_max_f(float v) {
    v = fmaxf(v, __int_as_float(dpp_ror<1>(__float_as_int(v))));
    v = fmaxf(v, __int_as_float(dpp_ror<2>(__float_as_int(v))));
    v = fmaxf(v, __int_as_float(dpp_ror<4>(__float_as_int(v))));
    v = fmaxf(v, __int_as_float(dpp_ror<8>(__float_as_int(v))));
    int iv = __float_as_int(v);
    v = fmaxf(v, __int_as_float(__builtin_amdgcn_update_dpp(iv, iv, 0x142, 0xf, 0xf, false)));
    iv = __float_as_int(v);
    v = fmaxf(v, __int_as_float(__builtin_amdgcn_update_dpp(iv, iv, 0x143, 0xf, 0xf, false)));
    return __int_as_float(__builtin_amdgcn_readlane(__float_as_int(v), 63));
}

__device__ __forceinline__ int wave_max_i(int v) {
    v = max(v, dpp_ror<1>(v));
    v = max(v, dpp_ror<2>(v));
    v = max(v, dpp_ror<4>(v));
    v = max(v, dpp_ror<8>(v));
    v = max(v, __builtin_amdgcn_update_dpp(v, v, 0x142, 0xf, 0xf, false));
    v = max(v, __builtin_amdgcn_update_dpp(v, v, 0x143, 0xf, 0xf, false));
    return __builtin_amdgcn_readlane(v, 63);
}

__device__ __forceinline__ float wave_scan_add(float v, int lane) {
    v += __int_as_float(dpp_shr<1>(__float_as_int(v)));
    v += __int_as_float(dpp_shr<2>(__float_as_int(v)));
    v += __int_as_float(dpp_shr<4>(__float_as_int(v)));
    v += __int_as_float(dpp_shr<8>(__float_as_int(v)));
    float s15 = __int_as_float(__builtin_amdgcn_readlane(__float_as_int(v), 15));
    float s31 = __int_as_float(__builtin_amdgcn_readlane(__float_as_int(v), 31));
    float s47 = __int_as_float(__builtin_amdgcn_readlane(__float_as_int(v), 47));
    int row = lane >> 4;
    if (row >= 1) v += s15;
    if (row >= 2) v += s31;
    if (row >= 3) v += s47;
    return v;
}

__device__ __forceinline__ int wave_scanmax_i(int v, int lane) {
    v = max(v, dpp_shr<1>(v));
    v = max(v, dpp_shr<2>(v));
    v = max(v, dpp_shr<4>(v));
    v = max(v, dpp_shr<8>(v));
    int r15 = __builtin_amdgcn_readlane(v, 15);
    int r31 = __builtin_amdgcn_readlane(v, 31);
    int r47 = __builtin_amdgcn_readlane(v, 47);
    int row = lane >> 4;
    if (row >= 1) v = max(v, r15);
    if (row >= 2) v = max(v, r31);
    if (row >= 3) v = max(v, r47);
    return v;
}

// cubic Lagrange at x (node units, 33-node row, clamped)
__device__ __forceinline__ float cubic_at(const float* __restrict__ row, float x) {
    int j = (int)floorf(x);
    j = j < 0 ? 0 : (j > 31 ? 31 : j);
    int st = j - 1;
    st = st < 0 ? 0 : (st > 29 ? 29 : st);
    float uu = x - (float)st;
    float um0 = uu, um1 = uu - 1.f, um2 = uu - 2.f, um3 = uu - 3.f;
    float c0 = um1 * um2 * um3 * (-1.f / 6.f);
    float c1 = um0 * um2 * um3 * (0.5f);
    float c2 = um0 * um1 * um3 * (-0.5f);
    float c3 = um0 * um1 * um2 * (1.f / 6.f);
    return c0 * row[st] + c1 * row[st + 1] + c2 * row[st + 2] + c3 * row[st + 3];
}

// exact count of slots i in [0,512) with fl(i+u) <= C, branchless +-2 fixup
__device__ __forceinline__ int count_le(float C, float u) {
    int h = (int)floorf(C - u);
    h = h < -1 ? -1 : (h > 511 ? 511 : h);
    h += (int)((h < 511) && (((float)(h + 1) + u) <= C));
    h += (int)((h < 511) && (((float)(h + 1) + u) <= C));
    h -= (int)((h >= 0) && (((float)h + u) > C));
    h -= (int)((h >= 0) && (((float)h + u) > C));
    return h + 1;
}

union ShU {
    struct {
        float As[5][33];
        float srow[5], irow[5];
        float Bs[32][512];
        float red[5][8];
    } p1;
    struct {
        float vt[TS][GV];      // 24704 f
        float ztI[TS][GI];     // 4224 f
        float vocs[GV];        // 193 f
        float zt2d[TAB2D];     // 1089 f
        float socs[2][NP];     // 1024 f
        float cur[TS], vm[TS], uu[TS];
        float redM[8], redT[8];
        int marker[NP];
    } p2;                      // ~125.6 KiB total
    float tile[32][33];
};

__global__ __launch_bounds__(512, 1) void k_all(
    const float* __restrict__ soc_init, const float* __restrict__ current,
    const float* __restrict__ vmeas, const float* __restrict__ u,
    const float* __restrict__ noise,
    const float* __restrict__ w1, const float* __restrict__ b1,
    const float* __restrict__ w2, const float* __restrict__ b2,
    const float* __restrict__ w3, const float* __restrict__ b3,
    float* __restrict__ zpart, float* __restrict__ vbuf, float* __restrict__ sbuf,
    int* __restrict__ syncv, float* __restrict__ out)
{
    __shared__ ShU sh;
    const int tid = threadIdx.x;
    const int bid = blockIdx.x;
    const int lane = tid & 63;
    const int wv = tid >> 6;

    // ================= phase 1: Z(s,I) table, 1089 rows x 512 cols =========
    if (bid < 218) {
        const int r0 = bid * 5;
        if (tid < 5) {
            int r = r0 + tid; if (r > TAB2D - 1) r = TAB2D - 1;
            int si = r / GI, ii = r - si * GI;
            sh.p1.srow[tid] = (float)si * (1.0f / 32.0f);
            sh.p1.irow[tid] = (float)ii * (1.0f / 32.0f);
        }
        __syncthreads();
        float acc[5] = {0.f, 0.f, 0.f, 0.f, 0.f};
        for (int kk = 0; kk < 1024; kk += 32) {
            if (tid < 160) {
                int r = tid >> 5, k = tid & 31, kc = kk + k;
                float pre = sh.p1.srow[r] * w1[kc] + sh.p1.irow[r] * w1[1024 + kc] + b1[kc];
                sh.p1.As[r][k] = sigmoid_jax(pre);
            }
            #pragma unroll
            for (int jj = 0; jj < 8; ++jj) {
                int vi = tid + jj * 512;
                int k = vi >> 7, c4 = vi & 127;
                *(float4*)&sh.p1.Bs[k][c4 * 4] = *(const float4*)&w2[(kk + k) * 512 + c4 * 4];
            }
            __syncthreads();
            #pragma unroll
            for (int k = 0; k < 32; ++k) {
                float bv = sh.p1.Bs[k][tid];
                #pragma unroll
                for (int r = 0; r < 5; ++r) acc[r] += sh.p1.As[r][k] * bv;
            }
            __syncthreads();
        }
        float b2c = b2[tid], w3c = w3[tid];
        #pragma unroll
        for (int r = 0; r < 5; ++r) {
            float zp = w3c * sigmoid_jax(acc[r] + b2c);
            #pragma unroll
            for (int mm = 1; mm < 64; mm <<= 1) zp += __shfl_xor(zp, mm);
            if (lane == 0) sh.p1.red[r][wv] = zp;
        }
        __syncthreads();
        if (tid < 5 && (r0 + tid) < TAB2D) {
            float s = 0.f;
            #pragma unroll
            for (int w = 0; w < 8; ++w) s += sh.p1.red[tid][w];
            zpart[r0 + tid] = s;
        }
        __syncthreads();   // done with p1 LDS before any reuse
    }

    // arrive (device-scope)
    if (tid == 0) { __threadfence(); atomicAdd(&syncv[0], 1); }

    if (bid == 0) {
        // ============= phase 2: sequential filter (1 block) =================
        if (tid == 0) {
            while (atomicAdd(&syncv[0], 0) < NB) __builtin_amdgcn_s_sleep(7);
            __threadfence();
        }
        __syncthreads();

        // ---- preamble: tables ----
        float bb3 = b3[0];
        for (int j = tid; j < TAB2D; j += 512) sh.p2.zt2d[j] = zpart[j] + bb3;
        if (tid < TS) { sh.p2.cur[tid] = current[tid]; sh.p2.vm[tid] = vmeas[tid]; sh.p2.uu[tid] = u[tid]; }
        if (tid < GV) sh.p2.vocs[tid] = vocf((float)tid * (1.0f / 192.0f));
        sh.p2.marker[tid] = 0;
        __syncthreads();
        for (int idx = tid; idx < TS * GI; idx += 512) {
            int t = idx / GI, g = idx - t * GI;
            sh.p2.ztI[t][g] = cubic_at(&sh.p2.zt2d[g * GI], sh.p2.cur[t] * 32.f);
        }
        __syncthreads();
        for (int idx = tid; idx < TS * GV; idx += 512) {
            int t = idx / GV, gg = idx - t * GV;
            float xs = (float)gg * (32.0f / 192.0f);
            sh.p2.vt[t][gg] = sh.p2.vocs[gg] - sh.p2.cur[t] * cubic_at(&sh.p2.ztI[t][0], xs);
        }
        __syncthreads();

        // ---- main loop ----
        float soc = soc_init[tid];
        float Iprev = sh.p2.cur[0];
        float V;
        {
            float x = soc * 192.f;
            int j = (int)x; j = j > 191 ? 191 : j;
            float f = x - (float)j;
            const float* vr = &sh.p2.vt[0][0];
            V = vr[j] + f * (vr[j + 1] - vr[j]);
        }
        float loss_acc = 0.f;
        const float LOG_NU = logf(19.947114020071635f);
        const float LOG_N = logf(512.f);
        float nz_cur = noise[tid];

        for (int t = 0; t < TS; ++t) {
            int tn = (t + 1 < TS) ? t + 1 : t;
            float nz_next = noise[tn * 512 + tid];   // stays in flight across LBARs

            soc = soc - Iprev * V * E_INV + F_STDc * nz_cur;
            soc = soc > 1.f ? 1.f : (soc < 0.f ? 1e-10f : soc);
            sh.p2.socs[t & 1][tid] = soc;

            float x = soc * 192.f;
            int j = (int)x; j = j > 191 ? 191 : j;
            float f = x - (float)j;
            const float* vr = &sh.p2.vt[t][0];
            V = vr[j] + f * (vr[j + 1] - vr[j]);

            float d = (V - sh.p2.vm[t]) * (1.f / G_STDc);
            float lw = LOG_NU - 0.5f * d * d;

            float m = wave_max_f(lw);
            float e = __expf(lw - m);
            float incl = wave_scan_add(e, lane);
            if (lane == 63) { sh.p2.redM[wv] = m; sh.p2.redT[wv] = incl; }
            LBAR();                                            // barrier 1

            float rm = sh.p2.redM[lane & 7];
            float rt = sh.p2.redT[lane & 7];
            float M = rm;
            M = fmaxf(M, __int_as_float(dpp_ror<1>(__float_as_int(M))));
            M = fmaxf(M, __int_as_float(dpp_ror<2>(__float_as_int(M))));
            M = fmaxf(M, __int_as_float(dpp_ror<4>(__float_as_int(M))));
            M = fmaxf(M, __int_as_float(dpp_ror<8>(__float_as_int(M))));
            float fw = __expf(rm - M);
            float term = rt * fw;
            float sc = term;
            sc += __int_as_float(dpp_shr<1>(__float_as_int(sc)));
            sc += __int_as_float(dpp_shr<2>(__float_as_int(sc)));
            sc += __int_as_float(dpp_shr<4>(__float_as_int(sc)));
            float S = __int_as_float(__builtin_amdgcn_readlane(__float_as_int(sc), 7));
            float off = 0.f;
            if (wv > 0) off = __int_as_float(__builtin_amdgcn_readlane(__float_as_int(sc), wv - 1));
            float fw_own = __int_as_float(__builtin_amdgcn_readlane(__float_as_int(fw), wv));
            loss_acc += M + __logf(S) - LOG_N;

            float C = 512.f * ((off + incl * fw_own) / S);
            int hi = count_le(C, sh.p2.uu[t]);
            if (hi < 512) atomicMax(&sh.p2.marker[hi], (t << 10) | (tid + 1));
            LBAR();                                            // barrier 2

            int pm = 0;
            for (int w = 0; w < wv; ++w) pm = max(pm, sh.p2.marker[w * 64 + lane]);
            pm = wave_max_i(pm);
            int v = wave_scanmax_i(sh.p2.marker[tid], lane);
            int sv = max(v, pm);
            int owner = ((sv >> 10) == t) ? (sv & 1023) : 0;
            owner = owner > 511 ? 511 : owner;
            float socr = sh.p2.socs[t & 1][owner];

            vbuf[t * 512 + tid] = V;
            sbuf[t * 512 + tid] = socr;
            soc = socr;
            Iprev = sh.p2.cur[t];
            nz_cur = nz_next;
        }
        if (tid == 0) out[0] = loss_acc;
        __syncthreads();   // drains vmcnt: all vbuf/sbuf stores complete
        if (tid == 0) { __threadfence(); atomicExch(&syncv[1], 1); }
        __syncthreads();
    } else {
        if (tid == 0) {
            while (atomicAdd(&syncv[1], 0) == 0) __builtin_amdgcn_s_sleep(7);
            __threadfence();
        }
        __syncthreads();
    }

    // ================= phase 3: transpose [128][512] -> [512][128] ==========
    if (bid < 128) {
        int arr = bid >> 6, rem = bid & 63, ti = rem >> 4, ii = rem & 15;
        const float* src = arr ? sbuf : vbuf;
        float* dst = out + 1 + arr * (NP * TS);
        int tx = tid & 31, ty = tid >> 5;   // ty 0..15
        #pragma unroll
        for (int h = 0; h < 32; h += 16)
            sh.tile[ty + h][tx] = src[(ti * 32 + ty + h) * 512 + ii * 32 + tx];
        __syncthreads();
        #pragma unroll
        for (int h = 0; h < 32; h += 16)
            dst[(ii * 32 + ty + h) * 128 + ti * 32 + tx] = sh.tile[tx][ty + h];
    }
}

extern "C" void kernel_launch(void* const* d_in, const int* in_sizes, int n_in,
                              void* d_out, int out_size, void* d_ws, size_t ws_size,
                              hipStream_t stream)
{
    const float* soc_init = (const float*)d_in[0];
    const float* current  = (const float*)d_in[1];
    const float* vmeas    = (const float*)d_in[2];
    const float* noise    = (const float*)d_in[3];
    const float* u        = (const float*)d_in[4];
    const float* w1 = (const float*)d_in[5];
    const float* b1 = (const float*)d_in[6];
    const float* w2 = (const float*)d_in[7];
    const float* b2 = (const float*)d_in[8];
    const float* w3 = (const float*)d_in[9];
    const float* b3 = (const float*)d_in[10];
    float* out = (float*)d_out;
    float* ws  = (float*)d_ws;

    float* zpart = ws;                         // 1089 floats
    float* vbuf  = ws + 1092;                  // 65536 floats (16B aligned)
    float* sbuf  = vbuf + NP * TS;             // 65536 floats
    int*   syncv = (int*)(sbuf + NP * TS);     // 2 ints

    hipMemsetAsync(syncv, 0, 2 * sizeof(int), stream);
    k_all<<<NB, 512, 0, stream>>>(soc_init, current, vmeas, u, noise,
                                  w1, b1, w2, b2, w3, b3,
                                  zpart, vbuf, sbuf, syncv, out);
}